// Round 1
// baseline (409.859 us; speedup 1.0000x reference)
//
#include <hip/hip_runtime.h>
#include <math.h>

#define BB 8
#define NN 2048
#define FIN 128
#define FOUT 64
#define TI 8
#define NEG_BIG -9e15f

// K1: h = x @ W  [B,N,64]; f1 = h . a[:64]; f2 = h . a[64:]
// 256 threads = 4 waves; each wave handles one (b,n) row; lane = output col.
__global__ __launch_bounds__(256) void gat_k1(const float* __restrict__ x,
                                              const float* __restrict__ W,
                                              const float* __restrict__ a,
                                              float* __restrict__ h,
                                              float* __restrict__ f1,
                                              float* __restrict__ f2) {
    __shared__ float xs[4][FIN];
    int t = threadIdx.x;
    int r = t >> 6;        // wave id in block -> row
    int c = t & 63;        // output column
    size_t bn = (size_t)blockIdx.x * 4 + r;   // 0 .. B*N-1
    const float* xr = x + bn * FIN;
    ((float2*)xs[r])[c] = ((const float2*)xr)[c];   // 128 floats per row
    // same wave writes & reads its xs row; no cross-wave dep
    float acc = 0.f;
#pragma unroll
    for (int k = 0; k < FIN; ++k) acc += xs[r][k] * W[k * FOUT + c];
    h[bn * FOUT + c] = acc;
    float p1 = acc * a[c];
    float p2 = acc * a[FOUT + c];
#pragma unroll
    for (int off = 32; off > 0; off >>= 1) {
        p1 += __shfl_down(p1, off, 64);
        p2 += __shfl_down(p2, off, 64);
    }
    if (c == 0) { f1[bn] = p1; f2[bn] = p2; }
}

// K2: per block: 8 i-rows of one batch. Masked tanh -> softmax (p in LDS)
// -> PV with register blocking -> elu.
__global__ __launch_bounds__(256) void gat_k2(const int* __restrict__ adj,
                                              const float* __restrict__ h,
                                              const float* __restrict__ f1,
                                              const float* __restrict__ f2,
                                              float* __restrict__ out) {
    __shared__ float pbuf[TI][NN];   // 64 KB; reused as reduction buffer
    __shared__ float f2s[NN];        // 8 KB
    __shared__ float rowsum[TI];
    __shared__ float rtmp[4];

    int t = threadIdx.x;
    int b = blockIdx.y;
    int i0 = blockIdx.x * TI;

    // stage f2[b,:] once
    const float* f2b = f2 + (size_t)b * NN;
    for (int j4 = t; j4 < NN / 4; j4 += 256)
        ((float4*)f2s)[j4] = ((const float4*)f2b)[j4];
    __syncthreads();

    for (int i = 0; i < TI; ++i) {
        int gi = i0 + i;
        const int* adjrow = adj + ((size_t)b * NN + (size_t)gi) * NN;
        float f1i = f1[(size_t)b * NN + gi];

        // pass 1: masked tanh, kept in registers; local max
        float4 vals[2];
        float lmax = NEG_BIG;
#pragma unroll
        for (int u = 0; u < 2; ++u) {
            int j4 = t + u * 256;                 // N/4 = 512 = 2*256
            int4 av = ((const int4*)adjrow)[j4];
            float4 fv = ((const float4*)f2s)[j4];
            float4 v;
            v.x = (av.x > 0) ? tanhf(f1i + fv.x) : NEG_BIG;
            v.y = (av.y > 0) ? tanhf(f1i + fv.y) : NEG_BIG;
            v.z = (av.z > 0) ? tanhf(f1i + fv.z) : NEG_BIG;
            v.w = (av.w > 0) ? tanhf(f1i + fv.w) : NEG_BIG;
            vals[u] = v;
            lmax = fmaxf(lmax, fmaxf(fmaxf(v.x, v.y), fmaxf(v.z, v.w)));
        }
        // block max
        float m = lmax;
#pragma unroll
        for (int off = 32; off > 0; off >>= 1) m = fmaxf(m, __shfl_down(m, off, 64));
        if ((t & 63) == 0) rtmp[t >> 6] = m;
        __syncthreads();
        m = fmaxf(fmaxf(rtmp[0], rtmp[1]), fmaxf(rtmp[2], rtmp[3]));
        __syncthreads();   // protect rtmp before reuse

        // pass 2: exp, store p to LDS, local sum
        float lsum = 0.f;
#pragma unroll
        for (int u = 0; u < 2; ++u) {
            int j4 = t + u * 256;
            float4 v = vals[u];
            float4 p;
            p.x = __expf(v.x - m);
            p.y = __expf(v.y - m);
            p.z = __expf(v.z - m);
            p.w = __expf(v.w - m);
            ((float4*)pbuf[i])[j4] = p;
            lsum += p.x + p.y + p.z + p.w;
        }
        float s = lsum;
#pragma unroll
        for (int off = 32; off > 0; off >>= 1) s += __shfl_down(s, off, 64);
        if ((t & 63) == 0) rtmp[t >> 6] = s;
        __syncthreads();
        if (t == 0) rowsum[i] = rtmp[0] + rtmp[1] + rtmp[2] + rtmp[3];
        __syncthreads();   // rtmp safe for next row; pbuf[i] visible
    }

    // PV: thread = (jp, cq); acc[TI][4] registers; p broadcast from LDS
    int cq = t & 15;       // column quad: cols 4*cq .. 4*cq+3
    int jp = t >> 4;       // j partition 0..15
    const float* hb = h + (size_t)b * NN * FOUT + cq * 4;
    float acc[TI][4];
#pragma unroll
    for (int i = 0; i < TI; ++i) {
        acc[i][0] = 0.f; acc[i][1] = 0.f; acc[i][2] = 0.f; acc[i][3] = 0.f;
    }
    for (int jj = jp; jj < NN; jj += 16) {
        float4 hv = *(const float4*)(hb + (size_t)jj * FOUT);
#pragma unroll
        for (int i = 0; i < TI; ++i) {
            float p = pbuf[i][jj];
            acc[i][0] = fmaf(p, hv.x, acc[i][0]);
            acc[i][1] = fmaf(p, hv.y, acc[i][1]);
            acc[i][2] = fmaf(p, hv.z, acc[i][2]);
            acc[i][3] = fmaf(p, hv.w, acc[i][3]);
        }
    }
    __syncthreads();       // done reading pbuf as p
    float* red = &pbuf[0][0];   // reuse: 16 partitions * TI * 64 = 32 KB
#pragma unroll
    for (int i = 0; i < TI; ++i) {
        float4 v = make_float4(acc[i][0], acc[i][1], acc[i][2], acc[i][3]);
        *((float4*)(red + ((size_t)(jp * TI + i) * FOUT) + cq * 4)) = v;
    }
    __syncthreads();
    for (int o = t; o < TI * FOUT; o += 256) {
        int i = o >> 6;
        int c = o & 63;
        float s = 0.f;
#pragma unroll
        for (int q = 0; q < 16; ++q) s += red[(size_t)(q * TI + i) * FOUT + c];
        s = s / rowsum[i];
        out[((size_t)b * NN + (size_t)(i0 + i)) * FOUT + c] = (s > 0.f) ? s : expm1f(s);
    }
}

extern "C" void kernel_launch(void* const* d_in, const int* in_sizes, int n_in,
                              void* d_out, int out_size, void* d_ws, size_t ws_size,
                              hipStream_t stream) {
    const float* x   = (const float*)d_in[0];   // [B,N,128]
    const int*   adj = (const int*)d_in[1];     // [B,N,N]
    const float* W   = (const float*)d_in[2];   // [128,64]
    const float* a   = (const float*)d_in[3];   // [128,1]
    float* out = (float*)d_out;                 // [B,N,64]

    float* h  = (float*)d_ws;                         // B*N*64 floats
    float* f1 = h + (size_t)BB * NN * FOUT;           // B*N
    float* f2 = f1 + (size_t)BB * NN;                 // B*N

    gat_k1<<<dim3(BB * NN / 4), dim3(256), 0, stream>>>(x, W, a, h, f1, f2);
    gat_k2<<<dim3(NN / TI, BB), dim3(256), 0, stream>>>(adj, h, f1, f2, out);
}

// Round 2
// 285.536 us; speedup vs baseline: 1.4354x; 1.4354x over previous
//
#include <hip/hip_runtime.h>
#include <math.h>

#define BB 8
#define NN 2048
#define FIN 128
#define FOUT 64
#define TI 8
#define TJ 512
#define NTILE (NN / TJ)

__device__ __forceinline__ float fast_tanh(float x) {
    float e = __expf(2.f * x);
    return 1.f - 2.f / (e + 1.f);
}

// K1: h = x @ W, f1 = h.a1, f2 = h.a2. Block: 16 rows, W staged in LDS.
__global__ __launch_bounds__(256, 2) void gat_k1(const float* __restrict__ x,
                                                 const float* __restrict__ W,
                                                 const float* __restrict__ a,
                                                 float* __restrict__ h,
                                                 float* __restrict__ f1,
                                                 float* __restrict__ f2) {
    __shared__ __attribute__((aligned(16))) float Wl[FIN][FOUT];  // 32 KB
    __shared__ __attribute__((aligned(16))) float xs[16][FIN];    // 8 KB
    int t = threadIdx.x;

    const float4* W4 = (const float4*)W;
    float4* Wl4 = (float4*)&Wl[0][0];
#pragma unroll
    for (int kk = 0; kk < 8; ++kk) Wl4[t + 256 * kk] = W4[t + 256 * kk];

    size_t row0 = (size_t)blockIdx.x * 16;
    const float4* x4 = (const float4*)(x + row0 * FIN);
    float4* xs4 = (float4*)&xs[0][0];
#pragma unroll
    for (int kk = 0; kk < 2; ++kk) xs4[t + 256 * kk] = x4[t + 256 * kk];
    __syncthreads();

    int c = t & 63;
    int rq = t >> 6;             // wave id -> base row; rows rq+4m
    float acc[4] = {0.f, 0.f, 0.f, 0.f};
#pragma unroll 8
    for (int k = 0; k < FIN; ++k) {
        float wv = Wl[k][c];     // 2-way bank (free), no conflict
        acc[0] = fmaf(xs[rq][k], wv, acc[0]);        // xs reads broadcast
        acc[1] = fmaf(xs[rq + 4][k], wv, acc[1]);
        acc[2] = fmaf(xs[rq + 8][k], wv, acc[2]);
        acc[3] = fmaf(xs[rq + 12][k], wv, acc[3]);
    }
    float a1c = a[c], a2c = a[FOUT + c];
#pragma unroll
    for (int m = 0; m < 4; ++m) {
        size_t bn = row0 + rq + 4 * m;
        h[bn * FOUT + c] = acc[m];
        float p1 = acc[m] * a1c;
        float p2 = acc[m] * a2c;
#pragma unroll
        for (int off = 32; off > 0; off >>= 1) {
            p1 += __shfl_down(p1, off, 64);
            p2 += __shfl_down(p2, off, 64);
        }
        if (c == 0) { f1[bn] = p1; f2[bn] = p2; }
    }
}

// K2: 8 i-rows per block, j tiled by 512. No max pass (tanh in [-1,1]).
__global__ __launch_bounds__(256, 4) void gat_k2(const int* __restrict__ adj,
                                                 const float* __restrict__ h,
                                                 const float* __restrict__ f1,
                                                 const float* __restrict__ f2,
                                                 float* __restrict__ out) {
    __shared__ __attribute__((aligned(16))) float pbuf[TI][TJ];       // 16 KB
    __shared__ __attribute__((aligned(16))) float f2s[NN];            // 8 KB
    __shared__ __attribute__((aligned(16))) float wred[4][TI][FOUT];  // 8 KB
    __shared__ __attribute__((aligned(16))) float rpart[TI][128];     // 4 KB
    __shared__ float f1s[TI];
    __shared__ float rinv[TI];

    int t = threadIdx.x;
    int b = blockIdx.y;
    int i0 = blockIdx.x * TI;

    const float* f2b = f2 + (size_t)b * NN;
    for (int j4 = t; j4 < NN / 4; j4 += 256)
        ((float4*)f2s)[j4] = ((const float4*)f2b)[j4];
    if (t < TI) f1s[t] = f1[(size_t)b * NN + i0 + t];
    __syncthreads();

    const int* adjbase = adj + ((size_t)b * NN + (size_t)i0) * NN;
    const float* hb = h + (size_t)b * NN * FOUT;

    int cq = t & 15;     // column quad 0..15 (coalesced h loads)
    int jp = t >> 4;     // j partition 0..15
    int prow = t >> 7;   // 0/1, p-phase row parity

    float acc[TI][4];
#pragma unroll
    for (int i = 0; i < TI; ++i)
        acc[i][0] = acc[i][1] = acc[i][2] = acc[i][3] = 0.f;
    float ps[4] = {0.f, 0.f, 0.f, 0.f};

    for (int tile = 0; tile < NTILE; ++tile) {
        int j0 = tile * TJ;
        // ---- p-phase: mask -> tanh -> exp, straight into LDS ----
#pragma unroll
        for (int kk = 0; kk < 4; ++kk) {
            int g = t + 256 * kk;
            int row = g >> 7;        // == 2*kk + prow (wave-uniform)
            int j4 = g & 127;
            int4 av = ((const int4*)(adjbase + (size_t)row * NN + j0))[j4];
            float4 fv = ((const float4*)(f2s + j0))[j4];
            float f1i = f1s[row];
            float4 p;
            p.x = (av.x > 0) ? __expf(fast_tanh(f1i + fv.x)) : 0.f;
            p.y = (av.y > 0) ? __expf(fast_tanh(f1i + fv.y)) : 0.f;
            p.z = (av.z > 0) ? __expf(fast_tanh(f1i + fv.z)) : 0.f;
            p.w = (av.w > 0) ? __expf(fast_tanh(f1i + fv.w)) : 0.f;
            ((float4*)pbuf[row])[j4] = p;
            ps[kk] += p.x + p.y + p.z + p.w;
        }
        __syncthreads();
        // ---- PV phase: acc[i][q] += p[i][j] * h[j][cq*4+q] ----
        for (int k = 0; k < TJ / 64; ++k) {
            int g4 = jp + 16 * k;          // float4 group within tile
            int jb = j0 + g4 * 4;
            const float* hp = hb + (size_t)jb * FOUT + cq * 4;
            float4 hv0 = *(const float4*)(hp);
            float4 hv1 = *(const float4*)(hp + FOUT);
            float4 hv2 = *(const float4*)(hp + 2 * FOUT);
            float4 hv3 = *(const float4*)(hp + 3 * FOUT);
#pragma unroll
            for (int i = 0; i < TI; ++i) {
                float4 p4 = ((float4*)pbuf[i])[g4];
                acc[i][0] = fmaf(p4.x, hv0.x, acc[i][0]);
                acc[i][1] = fmaf(p4.x, hv0.y, acc[i][1]);
                acc[i][2] = fmaf(p4.x, hv0.z, acc[i][2]);
                acc[i][3] = fmaf(p4.x, hv0.w, acc[i][3]);
                acc[i][0] = fmaf(p4.y, hv1.x, acc[i][0]);
                acc[i][1] = fmaf(p4.y, hv1.y, acc[i][1]);
                acc[i][2] = fmaf(p4.y, hv1.z, acc[i][2]);
                acc[i][3] = fmaf(p4.y, hv1.w, acc[i][3]);
                acc[i][0] = fmaf(p4.z, hv2.x, acc[i][0]);
                acc[i][1] = fmaf(p4.z, hv2.y, acc[i][1]);
                acc[i][2] = fmaf(p4.z, hv2.z, acc[i][2]);
                acc[i][3] = fmaf(p4.z, hv2.w, acc[i][3]);
                acc[i][0] = fmaf(p4.w, hv3.x, acc[i][0]);
                acc[i][1] = fmaf(p4.w, hv3.y, acc[i][1]);
                acc[i][2] = fmaf(p4.w, hv3.z, acc[i][2]);
                acc[i][3] = fmaf(p4.w, hv3.w, acc[i][3]);
            }
        }
        __syncthreads();
    }

    // ---- wave-internal reduction over this wave's 4 jp partitions ----
#pragma unroll
    for (int i = 0; i < TI; ++i)
#pragma unroll
        for (int q = 0; q < 4; ++q) {
            float v = acc[i][q];
            v += __shfl_down(v, 32, 64);
            v += __shfl_down(v, 16, 64);
            acc[i][q] = v;
        }
    int w = t >> 6;
    int lane = t & 63;
    if (lane < 16) {   // lane == cq for these lanes
#pragma unroll
        for (int i = 0; i < TI; ++i)
            *(float4*)&wred[w][i][lane * 4] =
                make_float4(acc[i][0], acc[i][1], acc[i][2], acc[i][3]);
    }
    // ---- rowsum partials -> inverse ----
#pragma unroll
    for (int kk = 0; kk < 4; ++kk) rpart[2 * kk + prow][t & 127] = ps[kk];
    __syncthreads();
    {
        int row = t >> 5, l = t & 31;
        float s = rpart[row][l] + rpart[row][l + 32] +
                  rpart[row][l + 64] + rpart[row][l + 96];
        s += __shfl_down(s, 16, 32);
        s += __shfl_down(s, 8, 32);
        s += __shfl_down(s, 4, 32);
        s += __shfl_down(s, 2, 32);
        s += __shfl_down(s, 1, 32);
        if (l == 0) rinv[row] = 1.f / s;
    }
    __syncthreads();
    // ---- epilogue: normalize + elu, coalesced stores ----
    float* ob = out + ((size_t)b * NN + (size_t)i0) * FOUT;
#pragma unroll
    for (int u = 0; u < 2; ++u) {
        int oo = t + 256 * u;
        int i = oo >> 6;
        int c = oo & 63;
        float s = (wred[0][i][c] + wred[1][i][c] + wred[2][i][c] + wred[3][i][c]) * rinv[i];
        ob[(size_t)i * FOUT + c] = (s > 0.f) ? s : expm1f(s);
    }
}

extern "C" void kernel_launch(void* const* d_in, const int* in_sizes, int n_in,
                              void* d_out, int out_size, void* d_ws, size_t ws_size,
                              hipStream_t stream) {
    const float* x   = (const float*)d_in[0];   // [B,N,128]
    const int*   adj = (const int*)d_in[1];     // [B,N,N]
    const float* W   = (const float*)d_in[2];   // [128,64]
    const float* a   = (const float*)d_in[3];   // [128,1]
    float* out = (float*)d_out;                 // [B,N,64]

    float* h  = (float*)d_ws;                         // B*N*64
    float* f1 = h + (size_t)BB * NN * FOUT;           // B*N
    float* f2 = f1 + (size_t)BB * NN;                 // B*N

    gat_k1<<<dim3(BB * NN / 16), dim3(256), 0, stream>>>(x, W, a, h, f1, f2);
    gat_k2<<<dim3(NN / TI, BB), dim3(256), 0, stream>>>(adj, h, f1, f2, out);
}